// Round 14
// baseline (879.650 us; speedup 1.0000x reference)
//
#include <hip/hip_runtime.h>
#include <float.h>

constexpr int cB = 8;
constexpr int cN = 2048;
constexpr int cKnn = 20;
constexpr float F_EPS = 1e-5f;
constexpr float F_SLOPE = 0.2f;

__device__ __forceinline__ float lrelu(float x){ return x >= 0.f ? x : F_SLOPE * x; }

typedef __bf16 bf16x8 __attribute__((ext_vector_type(8)));
typedef float  f32x4  __attribute__((ext_vector_type(4)));
union U16x8 { uint4 u; bf16x8 v; };

__device__ __forceinline__ unsigned short f2bf(float x){
    unsigned u = __builtin_bit_cast(unsigned, x);
    unsigned r = u + 0x7FFFu + ((u >> 16) & 1u);
    return (unsigned short)(r >> 16);
}
__device__ __forceinline__ float bf2f(unsigned short h){
    return __builtin_bit_cast(float, (unsigned)h << 16);
}
__device__ __forceinline__ bf16x8 ldfrag(const unsigned short* p){
    U16x8 t; t.u = *(const uint4*)p; return t.v;
}
__device__ __forceinline__ unsigned f2key(float s){
    unsigned u = __builtin_bit_cast(unsigned, s);
    return (s >= 0.f) ? (u | 0x80000000u) : ~u;
}

// ---------------- transpose x (B,3,N) -> xt (B,N,4) zero-padded, + xx ----------------
__global__ void k_transpose3(const float* __restrict__ x, float* __restrict__ xt, float* __restrict__ xx){
    int i = blockIdx.x * 256 + threadIdx.x;
    if(i >= cB * cN) return;
    int b = i / cN, n = i % cN;
    const float* xb = x + (size_t)b * 3 * cN;
    float a = xb[n], c = xb[cN + n], d = xb[2*cN + n];
    float* o = xt + (size_t)i * 4;
    o[0] = a; o[1] = c; o[2] = d; o[3] = 0.f;
    xx[i] = a*a + c*c + d*d;
}

// ---------------- all weight prep in one kernel ----------------
template<int Cin, int O, int CP>
__device__ __forceinline__ void prep_split_elem(const float* __restrict__ w, unsigned short* __restrict__ whl, int e){
    int c = e % CP, o2 = e / CP;
    float val = 0.f;
    if(c < Cin){
        if(o2 < O) val = w[o2 * 2 * Cin + c];
        else { int o = o2 - O; val = w[o * 2 * Cin + Cin + c] - w[o * 2 * Cin + c]; }
    }
    unsigned short h = f2bf(val);
    unsigned short l = f2bf(val - bf2f(h));
    whl[(size_t)o2 * 2 * CP + c] = h;
    whl[(size_t)o2 * 2 * CP + CP + c] = l;
}

__global__ void k_prepall(const float* __restrict__ w1, const float* __restrict__ w2,
                          const float* __restrict__ w3, const float* __restrict__ w4,
                          const float* __restrict__ w5,
                          float* __restrict__ ww, unsigned short* __restrict__ whl2,
                          unsigned short* __restrict__ whl3, unsigned short* __restrict__ whl4,
                          unsigned short* __restrict__ w5b){
    int e = blockIdx.x * 256 + threadIdx.x;
    if(e < 512){
        int op = e % 128, c = e / 128;
        float val = 0.f;
        if(c < 3){
            if(op < 64) val = w1[op * 6 + c];
            else { int o = op - 64; val = w1[o * 6 + 3 + c] - w1[o * 6 + c]; }
        }
        ww[e] = val;
        return;
    }
    e -= 512;
    if(e < 8192){ prep_split_elem<64, 64, 64>(w2, whl2, e); return; }
    e -= 8192;
    if(e < 16384){ prep_split_elem<64, 128, 64>(w3, whl3, e); return; }
    e -= 16384;
    if(e < 65536){ prep_split_elem<128, 256, 128>(w4, whl4, e); return; }
    e -= 65536;
    if(e < 524288) w5b[e] = f2bf(w5[e]);
}

// ---------------- fp32 score GEMM (layer 1, C=4 only), all 8 batches ----------------
template<int C>
__global__ __launch_bounds__(256) void k_score(const float* __restrict__ xt, const float* __restrict__ xx,
                                               float* __restrict__ S){
    __shared__ float at[16][68];
    __shared__ float bt[16][68];
    int tid = threadIdx.x;
    int j0 = blockIdx.x * 64, q0 = blockIdx.y * 64, b = blockIdx.z;
    const float* Xb = xt + (size_t)b * cN * C;
    int no = tid % 16, mo = tid / 16;
    float acc[4][4] = {};
    {
        if(tid < 64){
            float4 v = *(const float4*)(Xb + (size_t)(q0 + tid) * C);
            at[0][tid] = v.x; at[1][tid] = v.y; at[2][tid] = v.z; at[3][tid] = v.w;
            float4 w = *(const float4*)(Xb + (size_t)(j0 + tid) * C);
            bt[0][tid] = w.x; bt[1][tid] = w.y; bt[2][tid] = w.z; bt[3][tid] = w.w;
        }
        __syncthreads();
        #pragma unroll
        for(int c = 0; c < C; c++){
            float av[4] = { at[c][mo*4+0], at[c][mo*4+1], at[c][mo*4+2], at[c][mo*4+3] };
            float bv[4] = { bt[c][no*4+0], bt[c][no*4+1], bt[c][no*4+2], bt[c][no*4+3] };
            #pragma unroll
            for(int i2 = 0; i2 < 4; i2++)
                #pragma unroll
                for(int j2 = 0; j2 < 4; j2++)
                    acc[i2][j2] += av[i2] * bv[j2];
        }
    }
    const float* xxb = xx + (size_t)b * cN;
    float4 xv = *(const float4*)(xxb + j0 + no * 4);
    #pragma unroll
    for(int i2 = 0; i2 < 4; i2++){
        float4 o = make_float4(2.f*acc[i2][0] - xv.x, 2.f*acc[i2][1] - xv.y,
                               2.f*acc[i2][2] - xv.z, 2.f*acc[i2][3] - xv.w);
        *(float4*)(S + ((size_t)b * cN + q0 + mo * 4 + i2) * cN + j0 + no * 4) = o;
    }
}

// ---------------- split-bf16 MFMA score: S = 2*(HH+HL+LH) - xx[j], all 8 batches ----------------
template<int C>
__global__ __launch_bounds__(256) void k_score_mfma(const unsigned short* __restrict__ XHL,
                                                    const float* __restrict__ xx,
                                                    float* __restrict__ S){
    constexpr int SROW = 2 * C;
    constexpr int KST = C / 32;
    __shared__ unsigned short As[128 * 40];
    __shared__ unsigned short Bs[128 * 40];
    int tid = threadIdx.x;
    int lane = tid & 63, wave = tid >> 6;
    int wm = wave & 1, wn = wave >> 1;
    int q0 = blockIdx.y * 128, j0 = blockIdx.x * 128, b = blockIdx.z;
    const unsigned short* Xb = XHL + (size_t)b * cN * SROW;
    int m = lane & 15, quad = lane >> 4;
    f32x4 acc[4][4] = {};

    for(int seg = 0; seg < 3; seg++){
        int aoff = (seg == 2) ? C : 0;   // A: H,H,L
        int boff = (seg == 1) ? C : 0;   // B: H,L,H
        for(int kk = 0; kk < KST; kk++){
            __syncthreads();
            #pragma unroll
            for(int h = 0; h < 2; h++){
                int cidx = tid + h * 256;
                int row = cidx >> 2, cc = cidx & 3;
                *(uint4*)&As[row*40 + cc*8] = *(const uint4*)(Xb + (size_t)(q0 + row) * SROW + aoff + kk*32 + cc*8);
                *(uint4*)&Bs[row*40 + cc*8] = *(const uint4*)(Xb + (size_t)(j0 + row) * SROW + boff + kk*32 + cc*8);
            }
            __syncthreads();
            bf16x8 af[4], bfr[4];
            #pragma unroll
            for(int t = 0; t < 4; t++){
                af[t]  = ldfrag(&As[(wm*64 + t*16 + m)*40 + quad*8]);
                bfr[t] = ldfrag(&Bs[(wn*64 + t*16 + m)*40 + quad*8]);
            }
            #pragma unroll
            for(int i = 0; i < 4; i++)
                #pragma unroll
                for(int j = 0; j < 4; j++)
                    acc[i][j] = __builtin_amdgcn_mfma_f32_16x16x32_bf16(af[i], bfr[j], acc[i][j], 0, 0, 0);
        }
    }
    const float* xxb = xx + (size_t)b * cN;
    #pragma unroll
    for(int j = 0; j < 4; j++){
        int jj = j0 + wn*64 + j*16 + m;
        float xv = xxb[jj];
        #pragma unroll
        for(int i = 0; i < 4; i++){
            int r0 = q0 + wm*64 + i*16 + quad*4;
            #pragma unroll
            for(int r = 0; r < 4; r++)
                S[((size_t)b * cN + r0 + r) * cN + jj] = 2.f * acc[i][j][r] - xv;
        }
    }
}

// ---------------- select top-20: 4 waves/row, fp32 keys, vectorized loads ----------------
// Each wave scans 512 contiguous candidates (8/lane, 2x float4), exact local top-20,
// dumps to LDS; wave 0 merges 80 candidates (2/lane) exactly.
__global__ __launch_bounds__(256) void k_select(const float* __restrict__ S, int* __restrict__ idxout){
    __shared__ unsigned skey[84];
    __shared__ int      sidx[84];
    int tid = threadIdx.x;
    int w = tid >> 6, lane = tid & 63;
    int n = blockIdx.x;
    int b = blockIdx.y;
    const float* rowp = S + ((size_t)b * cN + n) * cN + w * 512 + lane * 8;
    unsigned key[8];
    {
        const float4* rp4 = (const float4*)rowp;
        float4 v0 = rp4[0], v1 = rp4[1];
        key[0]=f2key(v0.x); key[1]=f2key(v0.y); key[2]=f2key(v0.z); key[3]=f2key(v0.w);
        key[4]=f2key(v1.x); key[5]=f2key(v1.y); key[6]=f2key(v1.z); key[7]=f2key(v1.w);
    }
    unsigned T = 0; bool exact = false;
    for(int bit = 31; bit >= 0; bit--){
        unsigned test = T | (1u << bit);
        int c = 0;
        #pragma unroll
        for(int i = 0; i < 8; i++) c += (key[i] >= test) ? 1 : 0;
        #pragma unroll
        for(int off = 32; off; off >>= 1) c += __shfl_xor(c, off);
        if(c >= cKnn){
            T = test;
            if(c == cKnn){ exact = true; break; }
        }
    }
    int jbase = w * 512 + lane * 8;
    int pos = 0;
    if(exact){
        #pragma unroll
        for(int i = 0; i < 8; i++){
            bool hi = key[i] >= T;
            unsigned long long mm = __ballot(hi);
            if(hi){
                int r = __popcll(mm & ((1ull << lane) - 1ull));
                skey[w*20 + pos + r] = key[i];
                sidx[w*20 + pos + r] = jbase + i;
            }
            pos += __popcll(mm);
        }
    } else {
        int nab = 0;
        #pragma unroll
        for(int i = 0; i < 8; i++) nab += (key[i] > T) ? 1 : 0;
        #pragma unroll
        for(int off = 32; off; off >>= 1) nab += __shfl_xor(nab, off);
        int need = cKnn - nab;
        #pragma unroll
        for(int i = 0; i < 8; i++){
            bool hi = key[i] > T;
            unsigned long long mm = __ballot(hi);
            if(hi){
                int r = __popcll(mm & ((1ull << lane) - 1ull));
                skey[w*20 + pos + r] = key[i];
                sidx[w*20 + pos + r] = jbase + i;
            }
            pos += __popcll(mm);
        }
        for(int i = 0; i < 8 && need > 0; i++){
            bool eq = (key[i] == T);
            unsigned long long mm = __ballot(eq);
            int r = __popcll(mm & ((1ull << lane) - 1ull));
            if(eq && r < need){
                skey[w*20 + pos + r] = key[i];
                sidx[w*20 + pos + r] = jbase + i;
            }
            int t = __popcll(mm); t = t < need ? t : need;
            pos += t; need -= t;
        }
    }
    __syncthreads();
    if(w) return;
    // merge 80 candidates, 2 per lane
    unsigned ck[2]; int cj[2];
    #pragma unroll
    for(int s = 0; s < 2; s++){
        int id = lane + s * 64;
        bool v = id < 80;
        ck[s] = v ? skey[id] : 0u;
        cj[s] = v ? sidx[id] : 0;
    }
    unsigned Tg = 0; bool exg = false;
    for(int bit = 31; bit >= 0; bit--){
        unsigned test = Tg | (1u << bit);
        int c = 0;
        #pragma unroll
        for(int s = 0; s < 2; s++) c += (ck[s] >= test) ? 1 : 0;
        #pragma unroll
        for(int off = 32; off; off >>= 1) c += __shfl_xor(c, off);
        if(c >= cKnn){
            Tg = test;
            if(c == cKnn){ exg = true; break; }
        }
    }
    int* out = idxout + ((size_t)b * cN + n) * cKnn;
    int pos2 = 0;
    if(exg){
        #pragma unroll
        for(int s = 0; s < 2; s++){
            bool hi = (ck[s] >= Tg);
            unsigned long long mm = __ballot(hi);
            if(hi){ int r = __popcll(mm & ((1ull << lane) - 1ull)); out[pos2 + r] = cj[s]; }
            pos2 += __popcll(mm);
        }
    } else {
        #pragma unroll
        for(int s = 0; s < 2; s++){
            bool hi = (ck[s] > Tg);
            unsigned long long mm = __ballot(hi);
            if(hi){ int r = __popcll(mm & ((1ull << lane) - 1ull)); out[pos2 + r] = cj[s]; }
            pos2 += __popcll(mm);
        }
        int need = cKnn - pos2;
        #pragma unroll
        for(int s = 0; s < 2; s++){
            if(need <= 0) break;
            bool eq = (ck[s] == Tg);
            unsigned long long mm = __ballot(eq);
            int r = __popcll(mm & ((1ull << lane) - 1ull));
            if(eq && r < need) out[pos2 + r] = cj[s];
            int t = __popcll(mm); t = t < need ? t : need;
            pos2 += t; need -= t;
        }
    }
}

// ---------------- layer-1 fp32 UW GEMM ----------------
template<int K, int W2O>
__global__ __launch_bounds__(256) void k_uw(const float* __restrict__ xt, const float* __restrict__ ww,
                                            float* __restrict__ UW){
    __shared__ float at[16][68];
    __shared__ float bt[16][68];
    int tid = threadIdx.x;
    int o0 = blockIdx.x * 64, q0 = blockIdx.y * 64, b = blockIdx.z;
    const float* Xb = xt + (size_t)b * cN * K;
    int no = tid % 16, mo = tid / 16;
    float acc[4][4] = {};
    {
        if(tid < 64){
            float4 v = *(const float4*)(Xb + (size_t)(q0 + tid) * K);
            at[0][tid] = v.x; at[1][tid] = v.y; at[2][tid] = v.z; at[3][tid] = v.w;
            int cc = tid >> 4, n4 = tid & 15;
            float4 wv = *(const float4*)(ww + (size_t)cc * W2O + o0 + n4 * 4);
            bt[cc][n4*4+0] = wv.x; bt[cc][n4*4+1] = wv.y;
            bt[cc][n4*4+2] = wv.z; bt[cc][n4*4+3] = wv.w;
        }
        __syncthreads();
        #pragma unroll
        for(int c = 0; c < K; c++){
            float av[4] = { at[c][mo*4+0], at[c][mo*4+1], at[c][mo*4+2], at[c][mo*4+3] };
            float bv[4] = { bt[c][no*4+0], bt[c][no*4+1], bt[c][no*4+2], bt[c][no*4+3] };
            #pragma unroll
            for(int i2 = 0; i2 < 4; i2++)
                #pragma unroll
                for(int j2 = 0; j2 < 4; j2++)
                    acc[i2][j2] += av[i2] * bv[j2];
        }
    }
    #pragma unroll
    for(int i2 = 0; i2 < 4; i2++){
        float4 v = make_float4(acc[i2][0], acc[i2][1], acc[i2][2], acc[i2][3]);
        *(float4*)(UW + ((size_t)b * cN + q0 + mo * 4 + i2) * W2O + o0 + no * 4) = v;
    }
}

// ---------------- split-bf16 MFMA UW: UW = X · [W1|WD-W1]^T ----------------
template<int C, int W2O>
__global__ __launch_bounds__(256) void k_uw_mfma(const unsigned short* __restrict__ XHL,
                                                 const unsigned short* __restrict__ WHL,
                                                 float* __restrict__ UW){
    constexpr int SROW = 2 * C;
    constexpr int KST = C / 32;
    __shared__ unsigned short As[128 * 40];
    __shared__ unsigned short Bs[128 * 40];
    int tid = threadIdx.x;
    int lane = tid & 63, wave = tid >> 6;
    int wm = wave & 1, wn = wave >> 1;
    int n0 = blockIdx.x * 128, q0 = blockIdx.y * 128, b = blockIdx.z;
    const unsigned short* Xb = XHL + (size_t)b * cN * SROW;
    int m = lane & 15, quad = lane >> 4;
    f32x4 acc[4][4] = {};

    for(int seg = 0; seg < 3; seg++){
        int aoff = (seg == 2) ? C : 0;
        int boff = (seg == 1) ? C : 0;
        for(int kk = 0; kk < KST; kk++){
            __syncthreads();
            #pragma unroll
            for(int h = 0; h < 2; h++){
                int cidx = tid + h * 256;
                int row = cidx >> 2, cc = cidx & 3;
                *(uint4*)&As[row*40 + cc*8] = *(const uint4*)(Xb + (size_t)(q0 + row) * SROW + aoff + kk*32 + cc*8);
                *(uint4*)&Bs[row*40 + cc*8] = *(const uint4*)(WHL + (size_t)(n0 + row) * SROW + boff + kk*32 + cc*8);
            }
            __syncthreads();
            bf16x8 af[4], bfr[4];
            #pragma unroll
            for(int t = 0; t < 4; t++){
                af[t]  = ldfrag(&As[(wm*64 + t*16 + m)*40 + quad*8]);
                bfr[t] = ldfrag(&Bs[(wn*64 + t*16 + m)*40 + quad*8]);
            }
            #pragma unroll
            for(int i = 0; i < 4; i++)
                #pragma unroll
                for(int j = 0; j < 4; j++)
                    acc[i][j] = __builtin_amdgcn_mfma_f32_16x16x32_bf16(af[i], bfr[j], acc[i][j], 0, 0, 0);
        }
    }
    #pragma unroll
    for(int i = 0; i < 4; i++){
        int r0 = q0 + wm*64 + i*16 + quad*4;
        #pragma unroll
        for(int j = 0; j < 4; j++){
            int col = n0 + wn*64 + j*16 + m;
            #pragma unroll
            for(int r = 0; r < 4; r++)
                UW[((size_t)b * cN + r0 + r) * W2O + col] = acc[i][j][r];
        }
    }
}

// ---------------- gather-max + stats: XCD-pinned batches (id&7), 16 pts/block ----------------
template<int O>
__global__ __launch_bounds__(256) void k_gmax(const float* __restrict__ UW, const int* __restrict__ idx,
                                              float* __restrict__ Mbuf, float* __restrict__ bsum, float* __restrict__ bsq){
    constexpr int VEC = O / 64;
    constexpr int W2O = 2 * O;
    int id = blockIdx.x;
    int b = id & 7;
    int base = (id >> 3) * 16;
    int tid = threadIdx.x;
    int w = tid >> 6, l = tid & 63;
    const float* U = UW + (size_t)b * cN * W2O;
    float lsum[VEC] = {}, lsq[VEC] = {};
    for(int p = 0; p < 4; p++){
        int n = base + w * 4 + p;
        const int* ip = idx + ((size_t)b * cN + n) * cKnn;
        int jj[cKnn];
        #pragma unroll
        for(int k = 0; k < cKnn; k++) jj[k] = ip[k];
        float mx[VEC], su[VEC] = {}, s2[VEC] = {};
        #pragma unroll
        for(int v = 0; v < VEC; v++) mx[v] = -FLT_MAX;
        #pragma unroll
        for(int k = 0; k < cKnn; k++){
            const float* ur = U + (size_t)jj[k] * W2O + l * VEC;
            float uv[VEC];
            if constexpr (VEC == 4){ float4 t = *(const float4*)ur; uv[0]=t.x; uv[1]=t.y; uv[2]=t.z; uv[3]=t.w; }
            else if constexpr (VEC == 2){ float2 t = *(const float2*)ur; uv[0]=t.x; uv[1]=t.y; }
            else { uv[0] = *ur; }
            #pragma unroll
            for(int v = 0; v < VEC; v++){
                mx[v] = fmaxf(mx[v], uv[v]); su[v] += uv[v]; s2[v] += uv[v]*uv[v];
            }
        }
        const float* wr = U + (size_t)n * W2O + O + l * VEC;
        float w2[VEC];
        if constexpr (VEC == 4){ float4 t = *(const float4*)wr; w2[0]=t.x; w2[1]=t.y; w2[2]=t.z; w2[3]=t.w; }
        else if constexpr (VEC == 2){ float2 t = *(const float2*)wr; w2[0]=t.x; w2[1]=t.y; }
        else { w2[0] = *wr; }
        float* mp = Mbuf + ((size_t)b * cN + n) * O + l * VEC;
        if constexpr (VEC == 4){
            *(float4*)mp = make_float4(mx[0]+w2[0], mx[1]+w2[1], mx[2]+w2[2], mx[3]+w2[3]);
        } else if constexpr (VEC == 2){
            *(float2*)mp = make_float2(mx[0]+w2[0], mx[1]+w2[1]);
        } else {
            *mp = mx[0] + w2[0];
        }
        #pragma unroll
        for(int v = 0; v < VEC; v++){
            lsum[v] += su[v] + (float)cKnn * w2[v];
            lsq[v]  += s2[v] + 2.f * w2[v] * su[v] + (float)cKnn * w2[v] * w2[v];
        }
    }
    int bkt = id & 63;
    #pragma unroll
    for(int v = 0; v < VEC; v++){
        atomicAdd(&bsum[bkt * O + l * VEC + v], lsum[v]);
        atomicAdd(&bsq [bkt * O + l * VEC + v], lsq[v]);
    }
}

// ---------------- reduce buckets -> scale/shift ----------------
template<int O>
__global__ void k_redstats(const float* __restrict__ bsum, const float* __restrict__ bsq,
                           const float* __restrict__ g, const float* __restrict__ bb,
                           float2* __restrict__ stats, float invcnt){
    int o = threadIdx.x;
    if(o >= O) return;
    float s = 0.f, q = 0.f;
    for(int k = 0; k < 64; k++){ s += bsum[k * O + o]; q += bsq[k * O + o]; }
    float m = s * invcnt;
    float v = q * invcnt - m * m;
    float sc = g[o] * rsqrtf(v + F_EPS);
    stats[o] = make_float2(sc, bb[o] - m * sc);
}

// ---------------- fused normalize: catb bf16 + next-layer XHL hi/lo + XX ----------------
template<int O, bool WXT>
__global__ void k_normf(const float* __restrict__ Mbuf, const float2* __restrict__ stats,
                        unsigned short* __restrict__ catb, unsigned short* __restrict__ xhl,
                        float* __restrict__ xx, int ooff){
    __shared__ float part[4];
    int tid = threadIdx.x;
    size_t i = (size_t)blockIdx.x * 256 + tid;
    int o = i % O;
    size_t bn = i / O;
    float2 st = stats[o];
    float y = lrelu(Mbuf[i] * st.x + st.y);
    catb[bn * 512 + ooff + o] = f2bf(y);
    if constexpr (WXT){
        unsigned short h = f2bf(y);
        unsigned short l = f2bf(y - bf2f(h));
        xhl[bn * 2 * O + o] = h;
        xhl[bn * 2 * O + O + o] = l;
        float s = y * y;
        #pragma unroll
        for(int off = 32; off; off >>= 1) s += __shfl_xor(s, off);
        if constexpr (O == 64){
            if((tid & 63) == 0) xx[bn] = s;
        } else {
            int wv = tid >> 6;
            if((tid & 63) == 0) part[wv] = s;
            __syncthreads();
            if((tid & 127) == 0) xx[bn] = part[wv] + part[wv + 1];
        }
    }
}

// ---------------- bf16 MFMA head GEMM: z[b][o][n] = w5 · cat ----------------
__global__ __launch_bounds__(256) void k_gemm_z_mfma(const unsigned short* __restrict__ W5B,
                                                     const unsigned short* __restrict__ CATB,
                                                     float* __restrict__ z){
    __shared__ unsigned short As[128 * 40];
    __shared__ unsigned short Bs[128 * 40];
    int tid = threadIdx.x;
    int lane = tid & 63, wave = tid >> 6;
    int wm = wave & 1, wn = wave >> 1;
    int n0 = blockIdx.x * 128, o0 = blockIdx.y * 128, b = blockIdx.z;
    const unsigned short* Cb = CATB + (size_t)b * cN * 512;
    int m = lane & 15, quad = lane >> 4;
    f32x4 acc[4][4] = {};

    for(int kk = 0; kk < 16; kk++){
        __syncthreads();
        #pragma unroll
        for(int h = 0; h < 2; h++){
            int cidx = tid + h * 256;
            int row = cidx >> 2, cc = cidx & 3;
            *(uint4*)&As[row*40 + cc*8] = *(const uint4*)(W5B + (size_t)(o0 + row) * 512 + kk*32 + cc*8);
            *(uint4*)&Bs[row*40 + cc*8] = *(const uint4*)(Cb  + (size_t)(n0 + row) * 512 + kk*32 + cc*8);
        }
        __syncthreads();
        bf16x8 af[4], bfr[4];
        #pragma unroll
        for(int t = 0; t < 4; t++){
            af[t]  = ldfrag(&As[(wm*64 + t*16 + m)*40 + quad*8]);
            bfr[t] = ldfrag(&Bs[(wn*64 + t*16 + m)*40 + quad*8]);
        }
        #pragma unroll
        for(int i = 0; i < 4; i++)
            #pragma unroll
            for(int j = 0; j < 4; j++)
                acc[i][j] = __builtin_amdgcn_mfma_f32_16x16x32_bf16(af[i], bfr[j], acc[i][j], 0, 0, 0);
    }
    #pragma unroll
    for(int i = 0; i < 4; i++){
        int r0 = o0 + wm*64 + i*16 + quad*4;
        #pragma unroll
        for(int j = 0; j < 4; j++){
            int col = n0 + wn*64 + j*16 + m;
            #pragma unroll
            for(int r = 0; r < 4; r++)
                z[((size_t)b * 1024 + r0 + r) * cN + col] = acc[i][j][r];
        }
    }
}

// ---------------- z stats per channel ----------------
__global__ void k_zstats(const float* __restrict__ z, const float* __restrict__ g5,
                         const float* __restrict__ b5, float2* __restrict__ stats){
    int o = blockIdx.x;
    int tid = threadIdx.x;
    __shared__ float ss[256], sq[256];
    float s = 0.f, q = 0.f;
    for(int e = tid; e < cB * cN; e += 256){
        int b = e >> 11, n = e & 2047;
        float v = z[((size_t)b * 1024 + o) * cN + n];
        s += v; q += v * v;
    }
    ss[tid] = s; sq[tid] = q; __syncthreads();
    for(int st = 128; st; st >>= 1){
        if(tid < st){ ss[tid] += ss[tid + st]; sq[tid] += sq[tid + st]; }
        __syncthreads();
    }
    if(tid == 0){
        float m = ss[0] / (float)(cB * cN);
        float v = sq[0] / (float)(cB * cN) - m * m;
        float sc = g5[o] * rsqrtf(v + F_EPS);
        stats[o] = make_float2(sc, b5[o] - m * sc);
    }
}

// ---------------- pooling ----------------
__global__ void k_pool(const float* __restrict__ z, const float2* __restrict__ stats,
                       float* __restrict__ p){
    int o = blockIdx.x, b = blockIdx.y;
    int tid = threadIdx.x;
    float2 st = stats[o];
    const float* row = z + ((size_t)b * 1024 + o) * cN;
    float mx = -FLT_MAX, sm = 0.f;
    for(int n = tid; n < cN; n += 256){
        float y = lrelu(row[n] * st.x + st.y);
        mx = fmaxf(mx, y); sm += y;
    }
    __shared__ float smx[256], ssm[256];
    smx[tid] = mx; ssm[tid] = sm; __syncthreads();
    for(int st2 = 128; st2; st2 >>= 1){
        if(tid < st2){ smx[tid] = fmaxf(smx[tid], smx[tid + st2]); ssm[tid] += ssm[tid + st2]; }
        __syncthreads();
    }
    if(tid == 0){
        p[(size_t)b * 2048 + o] = smx[0];
        p[(size_t)b * 2048 + 1024 + o] = ssm[0] * (1.f / cN);
    }
}

// ---------------- FC layers ----------------
__global__ void k_fc1(const float* __restrict__ p, const float* __restrict__ lw1,
                      const float* __restrict__ g6, const float* __restrict__ b6,
                      float* __restrict__ h1){
    int f = blockIdx.x;
    int tid = threadIdx.x;
    const float* wrow = lw1 + (size_t)f * 2048;
    float acc[cB] = {};
    for(int i = tid; i < 2048; i += 64){
        float wv = wrow[i];
        #pragma unroll
        for(int b = 0; b < cB; b++) acc[b] += p[(size_t)b * 2048 + i] * wv;
    }
    #pragma unroll
    for(int b = 0; b < cB; b++){
        float v = acc[b];
        for(int off = 32; off; off >>= 1) v += __shfl_down(v, off);
        acc[b] = v;
    }
    if(tid == 0){
        float m = 0.f;
        #pragma unroll
        for(int b = 0; b < cB; b++) m += acc[b];
        m *= (1.f / cB);
        float var = 0.f;
        #pragma unroll
        for(int b = 0; b < cB; b++){ float d = acc[b] - m; var += d * d; }
        var *= (1.f / cB);
        float sc = g6[f] * rsqrtf(var + F_EPS);
        float sh = b6[f] - m * sc;
        #pragma unroll
        for(int b = 0; b < cB; b++) h1[(size_t)b * 512 + f] = lrelu(acc[b] * sc + sh);
    }
}

__global__ void k_fc2(const float* __restrict__ h1, const float* __restrict__ lw2,
                      const float* __restrict__ lb2, const float* __restrict__ g7,
                      const float* __restrict__ b7, float* __restrict__ h2){
    int f = blockIdx.x;
    int tid = threadIdx.x;
    const float* wrow = lw2 + (size_t)f * 512;
    float acc[cB] = {};
    for(int i = tid; i < 512; i += 64){
        float wv = wrow[i];
        #pragma unroll
        for(int b = 0; b < cB; b++) acc[b] += h1[(size_t)b * 512 + i] * wv;
    }
    #pragma unroll
    for(int b = 0; b < cB; b++){
        float v = acc[b];
        for(int off = 32; off; off >>= 1) v += __shfl_down(v, off);
        acc[b] = v;
    }
    if(tid == 0){
        float bias = lb2[f];
        #pragma unroll
        for(int b = 0; b < cB; b++) acc[b] += bias;
        float m = 0.f;
        #pragma unroll
        for(int b = 0; b < cB; b++) m += acc[b];
        m *= (1.f / cB);
        float var = 0.f;
        #pragma unroll
        for(int b = 0; b < cB; b++){ float d = acc[b] - m; var += d * d; }
        var *= (1.f / cB);
        float sc = g7[f] * rsqrtf(var + F_EPS);
        float sh = b7[f] - m * sc;
        #pragma unroll
        for(int b = 0; b < cB; b++) h2[(size_t)b * 256 + f] = lrelu(acc[b] * sc + sh);
    }
}

__global__ void k_fc3(const float* __restrict__ h2, const float* __restrict__ lw3,
                      const float* __restrict__ lb3, float* __restrict__ out){
    int cls = blockIdx.x;
    int tid = threadIdx.x;
    const float* wrow = lw3 + (size_t)cls * 256;
    float acc[cB] = {};
    for(int i = tid; i < 256; i += 64){
        float wv = wrow[i];
        #pragma unroll
        for(int b = 0; b < cB; b++) acc[b] += h2[(size_t)b * 256 + i] * wv;
    }
    #pragma unroll
    for(int b = 0; b < cB; b++){
        float v = acc[b];
        for(int off = 32; off; off >>= 1) v += __shfl_down(v, off);
        acc[b] = v;
    }
    if(tid == 0){
        float bias = lb3[cls];
        #pragma unroll
        for(int b = 0; b < cB; b++) out[(size_t)b * 40 + cls] = acc[b] + bias;
    }
}

// =====================================================================
extern "C" void kernel_launch(void* const* d_in, const int* in_sizes, int n_in,
                              void* d_out, int out_size, void* d_ws, size_t ws_size,
                              hipStream_t stream){
    (void)in_sizes; (void)n_in; (void)out_size; (void)ws_size;
    const float* x   = (const float*)d_in[0];
    const float* w1  = (const float*)d_in[1];
    const float* w2  = (const float*)d_in[2];
    const float* w3  = (const float*)d_in[3];
    const float* w4  = (const float*)d_in[4];
    const float* w5  = (const float*)d_in[5];
    const float* lw1 = (const float*)d_in[6];
    const float* lw2 = (const float*)d_in[7];
    const float* lb2 = (const float*)d_in[8];
    const float* lw3 = (const float*)d_in[9];
    const float* lb3 = (const float*)d_in[10];
    const float* g1 = (const float*)d_in[11]; const float* b1 = (const float*)d_in[12];
    const float* g2 = (const float*)d_in[13]; const float* b2 = (const float*)d_in[14];
    const float* g3 = (const float*)d_in[15]; const float* b3 = (const float*)d_in[16];
    const float* g4 = (const float*)d_in[17]; const float* b4 = (const float*)d_in[18];
    const float* g5 = (const float*)d_in[19]; const float* b5 = (const float*)d_in[20];
    const float* g6 = (const float*)d_in[21]; const float* b6 = (const float*)d_in[22];
    const float* g7 = (const float*)d_in[23]; const float* b7 = (const float*)d_in[24];

    char* base = (char*)d_ws;
    size_t off = 0;
    auto alloc = [&](size_t bytes) -> char* {
        char* pp = base + off;
        off += (bytes + 255) & ~(size_t)255;
        return pp;
    };
    float*  SC   = (float*) alloc(sizeof(float) * (size_t)cB * cN * cN);    // 134 MB score buffer
    float*  XT   = (float*) alloc(sizeof(float) * (size_t)cB * cN * 4);
    float*  Z    = (float*) alloc(sizeof(float) * (size_t)cB * 1024 * cN);  // UW + head z
    float*  MB   = (float*) alloc(sizeof(float) * (size_t)cB * cN * 256);
    int*    IDX  = (int*)   alloc(sizeof(int)   * (size_t)cB * cN * cKnn);
    float*  XX   = (float*) alloc(sizeof(float) * (size_t)cB * cN);
    float*  BS   = (float*) alloc(sizeof(float) * 4 * 2 * 64 * 256);
    float2* STATS= (float2*)alloc(sizeof(float2) * 1024);
    float*  WW   = (float*) alloc(sizeof(float) * 4 * 128);
    unsigned short* WHL2 = (unsigned short*)alloc(sizeof(short) * 128 * 128);
    unsigned short* WHL3 = (unsigned short*)alloc(sizeof(short) * 256 * 128);
    unsigned short* WHL4 = (unsigned short*)alloc(sizeof(short) * 512 * 256);
    unsigned short* XHL  = (unsigned short*)alloc(sizeof(short) * (size_t)cB * cN * 256);
    unsigned short* CATB = (unsigned short*)alloc(sizeof(short) * (size_t)cB * cN * 512);
    unsigned short* W5B  = (unsigned short*)alloc(sizeof(short) * 1024 * 512);
    float*  P    = (float*) alloc(sizeof(float) * (size_t)cB * 2048);
    float*  H1   = (float*) alloc(sizeof(float) * (size_t)cB * 512);
    float*  H2   = (float*) alloc(sizeof(float) * (size_t)cB * 256);
    float*  UW   = Z;
    float* BSUM0 = BS + 0 * 2 * 16384, *BSQ0 = BSUM0 + 16384;
    float* BSUM1 = BS + 1 * 2 * 16384, *BSQ1 = BSUM1 + 16384;
    float* BSUM2 = BS + 2 * 2 * 16384, *BSQ2 = BSUM2 + 16384;
    float* BSUM3 = BS + 3 * 2 * 16384, *BSQ3 = BSUM3 + 16384;

    const float invcnt = 1.f / (float)(cB * cN * cKnn);
    dim3 sc1Grid(cN / 64, cN / 64, cB);
    dim3 scmGrid(cN / 128, cN / 128, cB);
    dim3 selGrid(cN, cB);            // 1 row per block, 4 waves per row
    int gmBlocks = (cN / 16) * cB;

    // ---- prologue ----
    k_transpose3<<<64, 256, 0, stream>>>(x, XT, XX);
    k_prepall<<<(614912 + 255) / 256, 256, 0, stream>>>(w1, w2, w3, w4, w5, WW, WHL2, WHL3, WHL4, W5B);
    hipMemsetAsync(BS, 0, sizeof(float) * 4 * 2 * 16384, stream);

    // ---- layer 1 (Cin=3 pad 4, O=64): fp32 score/uw ----
    k_score<4><<<sc1Grid, 256, 0, stream>>>(XT, XX, SC);
    k_select<<<selGrid, 256, 0, stream>>>(SC, IDX);
    k_uw<4, 128><<<dim3(2, 32, cB), 256, 0, stream>>>(XT, WW, UW);
    k_gmax<64><<<gmBlocks, 256, 0, stream>>>(UW, IDX, MB, BSUM0, BSQ0);
    k_redstats<64><<<1, 256, 0, stream>>>(BSUM0, BSQ0, g1, b1, STATS, invcnt);
    k_normf<64, true><<<(cB * cN * 64) / 256, 256, 0, stream>>>(MB, STATS, CATB, XHL, XX, 0);

    // ---- layer 2 (Cin=64, O=64): split-bf16 MFMA ----
    k_score_mfma<64><<<scmGrid, 256, 0, stream>>>(XHL, XX, SC);
    k_select<<<selGrid, 256, 0, stream>>>(SC, IDX);
    k_uw_mfma<64, 128><<<dim3(1, 16, cB), 256, 0, stream>>>(XHL, WHL2, UW);
    k_gmax<64><<<gmBlocks, 256, 0, stream>>>(UW, IDX, MB, BSUM1, BSQ1);
    k_redstats<64><<<1, 256, 0, stream>>>(BSUM1, BSQ1, g2, b2, STATS, invcnt);
    k_normf<64, true><<<(cB * cN * 64) / 256, 256, 0, stream>>>(MB, STATS, CATB, XHL, XX, 64);

    // ---- layer 3 (Cin=64, O=128) ----
    k_score_mfma<64><<<scmGrid, 256, 0, stream>>>(XHL, XX, SC);
    k_select<<<selGrid, 256, 0, stream>>>(SC, IDX);
    k_uw_mfma<64, 256><<<dim3(2, 16, cB), 256, 0, stream>>>(XHL, WHL3, UW);
    k_gmax<128><<<gmBlocks, 256, 0, stream>>>(UW, IDX, MB, BSUM2, BSQ2);
    k_redstats<128><<<1, 256, 0, stream>>>(BSUM2, BSQ2, g3, b3, STATS, invcnt);
    k_normf<128, true><<<(cB * cN * 128) / 256, 256, 0, stream>>>(MB, STATS, CATB, XHL, XX, 128);

    // ---- layer 4 (Cin=128, O=256) ----
    k_score_mfma<128><<<scmGrid, 256, 0, stream>>>(XHL, XX, SC);
    k_select<<<selGrid, 256, 0, stream>>>(SC, IDX);
    k_uw_mfma<128, 512><<<dim3(4, 16, cB), 256, 0, stream>>>(XHL, WHL4, UW);
    k_gmax<256><<<gmBlocks, 256, 0, stream>>>(UW, IDX, MB, BSUM3, BSQ3);
    k_redstats<256><<<1, 256, 0, stream>>>(BSUM3, BSQ3, g4, b4, STATS, invcnt);
    k_normf<256, false><<<(cB * cN * 256) / 256, 256, 0, stream>>>(MB, STATS, CATB, nullptr, nullptr, 256);

    // ---- head ----
    k_gemm_z_mfma<<<dim3(cN / 128, 1024 / 128, cB), 256, 0, stream>>>(W5B, CATB, Z);
    k_zstats<<<1024, 256, 0, stream>>>(Z, g5, b5, STATS);
    k_pool<<<dim3(1024, cB), 256, 0, stream>>>(Z, STATS, P);
    k_fc1<<<512, 64, 0, stream>>>(P, lw1, g6, b6, H1);
    k_fc2<<<256, 64, 0, stream>>>(H1, lw2, lb2, g7, b7, H2);
    k_fc3<<<40, 64, 0, stream>>>(H2, lw3, lb3, (float*)d_out);
}

// Round 15
// 734.505 us; speedup vs baseline: 1.1976x; 1.1976x over previous
//
#include <hip/hip_runtime.h>
#include <float.h>

constexpr int cB = 8;
constexpr int cN = 2048;
constexpr int cKnn = 20;
constexpr float F_EPS = 1e-5f;
constexpr float F_SLOPE = 0.2f;

__device__ __forceinline__ float lrelu(float x){ return x >= 0.f ? x : F_SLOPE * x; }

typedef __bf16 bf16x8 __attribute__((ext_vector_type(8)));
typedef float  f32x4  __attribute__((ext_vector_type(4)));
union U16x8 { uint4 u; bf16x8 v; };

__device__ __forceinline__ unsigned short f2bf(float x){
    unsigned u = __builtin_bit_cast(unsigned, x);
    unsigned r = u + 0x7FFFu + ((u >> 16) & 1u);
    return (unsigned short)(r >> 16);
}
__device__ __forceinline__ float bf2f(unsigned short h){
    return __builtin_bit_cast(float, (unsigned)h << 16);
}
__device__ __forceinline__ bf16x8 ldfrag(const unsigned short* p){
    U16x8 t; t.u = *(const uint4*)p; return t.v;
}
__device__ __forceinline__ unsigned f2key(float s){
    unsigned u = __builtin_bit_cast(unsigned, s);
    return (s >= 0.f) ? (u | 0x80000000u) : ~u;
}

// ---------------- transpose x (B,3,N) -> xt (B,N,4) zero-padded, + xx ----------------
__global__ void k_transpose3(const float* __restrict__ x, float* __restrict__ xt, float* __restrict__ xx){
    int i = blockIdx.x * 256 + threadIdx.x;
    if(i >= cB * cN) return;
    int b = i / cN, n = i % cN;
    const float* xb = x + (size_t)b * 3 * cN;
    float a = xb[n], c = xb[cN + n], d = xb[2*cN + n];
    float* o = xt + (size_t)i * 4;
    o[0] = a; o[1] = c; o[2] = d; o[3] = 0.f;
    xx[i] = a*a + c*c + d*d;
}

// ---------------- all weight prep in one kernel ----------------
template<int Cin, int O, int CP>
__device__ __forceinline__ void prep_split_elem(const float* __restrict__ w, unsigned short* __restrict__ whl, int e){
    int c = e % CP, o2 = e / CP;
    float val = 0.f;
    if(c < Cin){
        if(o2 < O) val = w[o2 * 2 * Cin + c];
        else { int o = o2 - O; val = w[o * 2 * Cin + Cin + c] - w[o * 2 * Cin + c]; }
    }
    unsigned short h = f2bf(val);
    unsigned short l = f2bf(val - bf2f(h));
    whl[(size_t)o2 * 2 * CP + c] = h;
    whl[(size_t)o2 * 2 * CP + CP + c] = l;
}

__global__ void k_prepall(const float* __restrict__ w1, const float* __restrict__ w2,
                          const float* __restrict__ w3, const float* __restrict__ w4,
                          const float* __restrict__ w5,
                          float* __restrict__ ww, unsigned short* __restrict__ whl2,
                          unsigned short* __restrict__ whl3, unsigned short* __restrict__ whl4,
                          unsigned short* __restrict__ w5b){
    int e = blockIdx.x * 256 + threadIdx.x;
    if(e < 512){
        int op = e % 128, c = e / 128;
        float val = 0.f;
        if(c < 3){
            if(op < 64) val = w1[op * 6 + c];
            else { int o = op - 64; val = w1[o * 6 + 3 + c] - w1[o * 6 + c]; }
        }
        ww[e] = val;
        return;
    }
    e -= 512;
    if(e < 8192){ prep_split_elem<64, 64, 64>(w2, whl2, e); return; }
    e -= 8192;
    if(e < 16384){ prep_split_elem<64, 128, 64>(w3, whl3, e); return; }
    e -= 16384;
    if(e < 65536){ prep_split_elem<128, 256, 128>(w4, whl4, e); return; }
    e -= 65536;
    if(e < 524288) w5b[e] = f2bf(w5[e]);
}

// ---------------- fp32 score GEMM (layer 1, C=4 only), all 8 batches ----------------
template<int C>
__global__ __launch_bounds__(256) void k_score(const float* __restrict__ xt, const float* __restrict__ xx,
                                               float* __restrict__ S){
    __shared__ float at[16][68];
    __shared__ float bt[16][68];
    int tid = threadIdx.x;
    int j0 = blockIdx.x * 64, q0 = blockIdx.y * 64, b = blockIdx.z;
    const float* Xb = xt + (size_t)b * cN * C;
    int no = tid % 16, mo = tid / 16;
    float acc[4][4] = {};
    {
        if(tid < 64){
            float4 v = *(const float4*)(Xb + (size_t)(q0 + tid) * C);
            at[0][tid] = v.x; at[1][tid] = v.y; at[2][tid] = v.z; at[3][tid] = v.w;
            float4 w = *(const float4*)(Xb + (size_t)(j0 + tid) * C);
            bt[0][tid] = w.x; bt[1][tid] = w.y; bt[2][tid] = w.z; bt[3][tid] = w.w;
        }
        __syncthreads();
        #pragma unroll
        for(int c = 0; c < C; c++){
            float av[4] = { at[c][mo*4+0], at[c][mo*4+1], at[c][mo*4+2], at[c][mo*4+3] };
            float bv[4] = { bt[c][no*4+0], bt[c][no*4+1], bt[c][no*4+2], bt[c][no*4+3] };
            #pragma unroll
            for(int i2 = 0; i2 < 4; i2++)
                #pragma unroll
                for(int j2 = 0; j2 < 4; j2++)
                    acc[i2][j2] += av[i2] * bv[j2];
        }
    }
    const float* xxb = xx + (size_t)b * cN;
    float4 xv = *(const float4*)(xxb + j0 + no * 4);
    #pragma unroll
    for(int i2 = 0; i2 < 4; i2++){
        float4 o = make_float4(2.f*acc[i2][0] - xv.x, 2.f*acc[i2][1] - xv.y,
                               2.f*acc[i2][2] - xv.z, 2.f*acc[i2][3] - xv.w);
        *(float4*)(S + ((size_t)b * cN + q0 + mo * 4 + i2) * cN + j0 + no * 4) = o;
    }
}

// ---------------- split-bf16 MFMA score: S = 2*(HH+HL+LH) - xx[j], all 8 batches ----------------
template<int C>
__global__ __launch_bounds__(256) void k_score_mfma(const unsigned short* __restrict__ XHL,
                                                    const float* __restrict__ xx,
                                                    float* __restrict__ S){
    constexpr int SROW = 2 * C;
    constexpr int KST = C / 32;
    __shared__ unsigned short As[128 * 40];
    __shared__ unsigned short Bs[128 * 40];
    int tid = threadIdx.x;
    int lane = tid & 63, wave = tid >> 6;
    int wm = wave & 1, wn = wave >> 1;
    int q0 = blockIdx.y * 128, j0 = blockIdx.x * 128, b = blockIdx.z;
    const unsigned short* Xb = XHL + (size_t)b * cN * SROW;
    int m = lane & 15, quad = lane >> 4;
    f32x4 acc[4][4] = {};

    for(int seg = 0; seg < 3; seg++){
        int aoff = (seg == 2) ? C : 0;   // A: H,H,L
        int boff = (seg == 1) ? C : 0;   // B: H,L,H
        for(int kk = 0; kk < KST; kk++){
            __syncthreads();
            #pragma unroll
            for(int h = 0; h < 2; h++){
                int cidx = tid + h * 256;
                int row = cidx >> 2, cc = cidx & 3;
                *(uint4*)&As[row*40 + cc*8] = *(const uint4*)(Xb + (size_t)(q0 + row) * SROW + aoff + kk*32 + cc*8);
                *(uint4*)&Bs[row*40 + cc*8] = *(const uint4*)(Xb + (size_t)(j0 + row) * SROW + boff + kk*32 + cc*8);
            }
            __syncthreads();
            bf16x8 af[4], bfr[4];
            #pragma unroll
            for(int t = 0; t < 4; t++){
                af[t]  = ldfrag(&As[(wm*64 + t*16 + m)*40 + quad*8]);
                bfr[t] = ldfrag(&Bs[(wn*64 + t*16 + m)*40 + quad*8]);
            }
            #pragma unroll
            for(int i = 0; i < 4; i++)
                #pragma unroll
                for(int j = 0; j < 4; j++)
                    acc[i][j] = __builtin_amdgcn_mfma_f32_16x16x32_bf16(af[i], bfr[j], acc[i][j], 0, 0, 0);
        }
    }
    const float* xxb = xx + (size_t)b * cN;
    #pragma unroll
    for(int j = 0; j < 4; j++){
        int jj = j0 + wn*64 + j*16 + m;
        float xv = xxb[jj];
        #pragma unroll
        for(int i = 0; i < 4; i++){
            int r0 = q0 + wm*64 + i*16 + quad*4;
            #pragma unroll
            for(int r = 0; r < 4; r++)
                S[((size_t)b * cN + r0 + r) * cN + jj] = 2.f * acc[i][j][r] - xv;
        }
    }
}

// ---------------- select top-20: 2 waves/row, top-4 prefilter + cheap search + fallback ----------------
// Wave scans 1024 contiguous candidates (16/lane). Phase 1: branchless per-lane top-4 values.
// Phase 2: 20th-largest search over the 256-candidate multiset (4 regs/lane, cheap rounds).
// Soundness: if no lane has m4 > T, dropped keys <= T, so T == true 20th value; else fallback
// to full search over all 16 regs. Emission counts ties on the FULL key regs (exact set).
__global__ __launch_bounds__(256) void k_select(const float* __restrict__ S, int* __restrict__ idxout){
    __shared__ unsigned skey[2][44];
    __shared__ int      sidx[2][44];
    int tid = threadIdx.x;
    int wave = tid >> 6, lane = tid & 63;
    int row = wave >> 1;
    int w   = wave & 1;
    int n = blockIdx.x * 2 + row;
    int b = blockIdx.y;
    const float* rowp = S + ((size_t)b * cN + n) * cN + w * 1024 + lane * 16;
    unsigned key[16];
    {
        const float4* rp4 = (const float4*)rowp;
        float4 v0 = rp4[0], v1 = rp4[1], v2 = rp4[2], v3 = rp4[3];
        key[0]=f2key(v0.x); key[1]=f2key(v0.y); key[2]=f2key(v0.z); key[3]=f2key(v0.w);
        key[4]=f2key(v1.x); key[5]=f2key(v1.y); key[6]=f2key(v1.z); key[7]=f2key(v1.w);
        key[8]=f2key(v2.x); key[9]=f2key(v2.y); key[10]=f2key(v2.z); key[11]=f2key(v2.w);
        key[12]=f2key(v3.x); key[13]=f2key(v3.y); key[14]=f2key(v3.z); key[15]=f2key(v3.w);
    }
    // phase 1: per-lane exact top-4 values (update bottom-up so each line reads old uppers)
    unsigned m1 = 0, m2 = 0, m3 = 0, m4 = 0;
    #pragma unroll
    for(int i = 0; i < 16; i++){
        unsigned k = key[i];
        m4 = max(m4, min(m3, k));
        m3 = max(m3, min(m2, k));
        m2 = max(m2, min(m1, k));
        m1 = max(m1, k);
    }
    // phase 2: search over candidate multiset {m1..m4}
    unsigned T = 0;
    for(int bit = 31; bit >= 0; bit--){
        unsigned test = T | (1u << bit);
        int c = (m1 >= test) + (m2 >= test) + (m3 >= test) + (m4 >= test);
        #pragma unroll
        for(int off = 32; off; off >>= 1) c += __shfl_xor(c, off);
        if(c >= cKnn){
            T = test;
            if(c == cKnn) break;
        }
    }
    // soundness: any dropped key could exceed T only if its lane's m4 > T
    bool ok = (__ballot(m4 > T) == 0ull);
    if(!ok){
        // fallback: full search over all 16 regs (rare)
        T = 0;
        for(int bit = 31; bit >= 0; bit--){
            unsigned test = T | (1u << bit);
            int c = 0;
            #pragma unroll
            for(int i = 0; i < 16; i++) c += (key[i] >= test) ? 1 : 0;
            #pragma unroll
            for(int off = 32; off; off >>= 1) c += __shfl_xor(c, off);
            if(c >= cKnn){
                T = test;
                if(c == cKnn) break;
            }
        }
    }
    // full packed counts: cge (low 16) and cgt (high 16) in one reduce
    int pc = 0;
    #pragma unroll
    for(int i = 0; i < 16; i++){
        pc += (key[i] >= T) ? 1 : 0;
        pc += (key[i] >  T) ? 0x10000 : 0;
    }
    #pragma unroll
    for(int off = 32; off; off >>= 1) pc += __shfl_xor(pc, off);
    int cge = pc & 0xFFFF;
    int nab = pc >> 16;
    bool exact = (cge == cKnn);

    int jbase = w * 1024 + lane * 16;
    int pos = 0;
    if(exact){
        #pragma unroll
        for(int i = 0; i < 16; i++){
            bool hi = key[i] >= T;
            unsigned long long mm = __ballot(hi);
            if(hi){
                int r = __popcll(mm & ((1ull << lane) - 1ull));
                skey[row][w*20 + pos + r] = key[i];
                sidx[row][w*20 + pos + r] = jbase + i;
            }
            pos += __popcll(mm);
        }
    } else {
        int need = cKnn - nab;
        #pragma unroll
        for(int i = 0; i < 16; i++){
            bool hi = key[i] > T;
            unsigned long long mm = __ballot(hi);
            if(hi){
                int r = __popcll(mm & ((1ull << lane) - 1ull));
                skey[row][w*20 + pos + r] = key[i];
                sidx[row][w*20 + pos + r] = jbase + i;
            }
            pos += __popcll(mm);
        }
        for(int i = 0; i < 16 && need > 0; i++){
            bool eq = (key[i] == T);
            unsigned long long mm = __ballot(eq);
            int r = __popcll(mm & ((1ull << lane) - 1ull));
            if(eq && r < need){
                skey[row][w*20 + pos + r] = key[i];
                sidx[row][w*20 + pos + r] = jbase + i;
            }
            int t = __popcll(mm); t = t < need ? t : need;
            pos += t; need -= t;
        }
    }
    __syncthreads();
    if(w) return;
    // merge 40 candidates (1/lane), exact global top-20
    unsigned k40 = (lane < 40) ? skey[row][lane] : 0u;
    int      j40 = (lane < 40) ? sidx[row][lane] : 0;
    unsigned Tg = 0; bool ex = false;
    for(int bit = 31; bit >= 0; bit--){
        unsigned test = Tg | (1u << bit);
        int c = __popcll(__ballot((lane < 40) && (k40 >= test)));
        if(c >= cKnn){
            Tg = test;
            if(c == cKnn){ ex = true; break; }
        }
    }
    int* out = idxout + ((size_t)b * cN + n) * cKnn;
    if(ex){
        bool hi = (lane < 40) && (k40 >= Tg);
        unsigned long long mm = __ballot(hi);
        if(hi){ int r = __popcll(mm & ((1ull << lane) - 1ull)); out[r] = j40; }
    } else {
        bool hi = (lane < 40) && (k40 > Tg);
        unsigned long long mm = __ballot(hi);
        if(hi){ int r = __popcll(mm & ((1ull << lane) - 1ull)); out[r] = j40; }
        int nab2 = __popcll(mm);
        int need = cKnn - nab2;
        bool eq = (lane < 40) && (k40 == Tg);
        unsigned long long me = __ballot(eq);
        int r = __popcll(me & ((1ull << lane) - 1ull));
        if(eq && r < need) out[nab2 + r] = j40;
    }
}

// ---------------- layer-1 fp32 UW GEMM ----------------
template<int K, int W2O>
__global__ __launch_bounds__(256) void k_uw(const float* __restrict__ xt, const float* __restrict__ ww,
                                            float* __restrict__ UW){
    __shared__ float at[16][68];
    __shared__ float bt[16][68];
    int tid = threadIdx.x;
    int o0 = blockIdx.x * 64, q0 = blockIdx.y * 64, b = blockIdx.z;
    const float* Xb = xt + (size_t)b * cN * K;
    int no = tid % 16, mo = tid / 16;
    float acc[4][4] = {};
    {
        if(tid < 64){
            float4 v = *(const float4*)(Xb + (size_t)(q0 + tid) * K);
            at[0][tid] = v.x; at[1][tid] = v.y; at[2][tid] = v.z; at[3][tid] = v.w;
            int cc = tid >> 4, n4 = tid & 15;
            float4 wv = *(const float4*)(ww + (size_t)cc * W2O + o0 + n4 * 4);
            bt[cc][n4*4+0] = wv.x; bt[cc][n4*4+1] = wv.y;
            bt[cc][n4*4+2] = wv.z; bt[cc][n4*4+3] = wv.w;
        }
        __syncthreads();
        #pragma unroll
        for(int c = 0; c < K; c++){
            float av[4] = { at[c][mo*4+0], at[c][mo*4+1], at[c][mo*4+2], at[c][mo*4+3] };
            float bv[4] = { bt[c][no*4+0], bt[c][no*4+1], bt[c][no*4+2], bt[c][no*4+3] };
            #pragma unroll
            for(int i2 = 0; i2 < 4; i2++)
                #pragma unroll
                for(int j2 = 0; j2 < 4; j2++)
                    acc[i2][j2] += av[i2] * bv[j2];
        }
    }
    #pragma unroll
    for(int i2 = 0; i2 < 4; i2++){
        float4 v = make_float4(acc[i2][0], acc[i2][1], acc[i2][2], acc[i2][3]);
        *(float4*)(UW + ((size_t)b * cN + q0 + mo * 4 + i2) * W2O + o0 + no * 4) = v;
    }
}

// ---------------- split-bf16 MFMA UW: UW = X · [W1|WD-W1]^T ----------------
template<int C, int W2O>
__global__ __launch_bounds__(256) void k_uw_mfma(const unsigned short* __restrict__ XHL,
                                                 const unsigned short* __restrict__ WHL,
                                                 float* __restrict__ UW){
    constexpr int SROW = 2 * C;
    constexpr int KST = C / 32;
    __shared__ unsigned short As[128 * 40];
    __shared__ unsigned short Bs[128 * 40];
    int tid = threadIdx.x;
    int lane = tid & 63, wave = tid >> 6;
    int wm = wave & 1, wn = wave >> 1;
    int n0 = blockIdx.x * 128, q0 = blockIdx.y * 128, b = blockIdx.z;
    const unsigned short* Xb = XHL + (size_t)b * cN * SROW;
    int m = lane & 15, quad = lane >> 4;
    f32x4 acc[4][4] = {};

    for(int seg = 0; seg < 3; seg++){
        int aoff = (seg == 2) ? C : 0;
        int boff = (seg == 1) ? C : 0;
        for(int kk = 0; kk < KST; kk++){
            __syncthreads();
            #pragma unroll
            for(int h = 0; h < 2; h++){
                int cidx = tid + h * 256;
                int row = cidx >> 2, cc = cidx & 3;
                *(uint4*)&As[row*40 + cc*8] = *(const uint4*)(Xb + (size_t)(q0 + row) * SROW + aoff + kk*32 + cc*8);
                *(uint4*)&Bs[row*40 + cc*8] = *(const uint4*)(WHL + (size_t)(n0 + row) * SROW + boff + kk*32 + cc*8);
            }
            __syncthreads();
            bf16x8 af[4], bfr[4];
            #pragma unroll
            for(int t = 0; t < 4; t++){
                af[t]  = ldfrag(&As[(wm*64 + t*16 + m)*40 + quad*8]);
                bfr[t] = ldfrag(&Bs[(wn*64 + t*16 + m)*40 + quad*8]);
            }
            #pragma unroll
            for(int i = 0; i < 4; i++)
                #pragma unroll
                for(int j = 0; j < 4; j++)
                    acc[i][j] = __builtin_amdgcn_mfma_f32_16x16x32_bf16(af[i], bfr[j], acc[i][j], 0, 0, 0);
        }
    }
    #pragma unroll
    for(int i = 0; i < 4; i++){
        int r0 = q0 + wm*64 + i*16 + quad*4;
        #pragma unroll
        for(int j = 0; j < 4; j++){
            int col = n0 + wn*64 + j*16 + m;
            #pragma unroll
            for(int r = 0; r < 4; r++)
                UW[((size_t)b * cN + r0 + r) * W2O + col] = acc[i][j][r];
        }
    }
}

// ---------------- gather-max + stats: XCD-pinned batches (id&7), 16 pts/block ----------------
template<int O>
__global__ __launch_bounds__(256) void k_gmax(const float* __restrict__ UW, const int* __restrict__ idx,
                                              float* __restrict__ Mbuf, float* __restrict__ bsum, float* __restrict__ bsq){
    constexpr int VEC = O / 64;
    constexpr int W2O = 2 * O;
    int id = blockIdx.x;
    int b = id & 7;
    int base = (id >> 3) * 16;
    int tid = threadIdx.x;
    int w = tid >> 6, l = tid & 63;
    const float* U = UW + (size_t)b * cN * W2O;
    float lsum[VEC] = {}, lsq[VEC] = {};
    for(int p = 0; p < 4; p++){
        int n = base + w * 4 + p;
        const int* ip = idx + ((size_t)b * cN + n) * cKnn;
        int jj[cKnn];
        #pragma unroll
        for(int k = 0; k < cKnn; k++) jj[k] = ip[k];
        float mx[VEC], su[VEC] = {}, s2[VEC] = {};
        #pragma unroll
        for(int v = 0; v < VEC; v++) mx[v] = -FLT_MAX;
        #pragma unroll
        for(int k = 0; k < cKnn; k++){
            const float* ur = U + (size_t)jj[k] * W2O + l * VEC;
            float uv[VEC];
            if constexpr (VEC == 4){ float4 t = *(const float4*)ur; uv[0]=t.x; uv[1]=t.y; uv[2]=t.z; uv[3]=t.w; }
            else if constexpr (VEC == 2){ float2 t = *(const float2*)ur; uv[0]=t.x; uv[1]=t.y; }
            else { uv[0] = *ur; }
            #pragma unroll
            for(int v = 0; v < VEC; v++){
                mx[v] = fmaxf(mx[v], uv[v]); su[v] += uv[v]; s2[v] += uv[v]*uv[v];
            }
        }
        const float* wr = U + (size_t)n * W2O + O + l * VEC;
        float w2[VEC];
        if constexpr (VEC == 4){ float4 t = *(const float4*)wr; w2[0]=t.x; w2[1]=t.y; w2[2]=t.z; w2[3]=t.w; }
        else if constexpr (VEC == 2){ float2 t = *(const float2*)wr; w2[0]=t.x; w2[1]=t.y; }
        else { w2[0] = *wr; }
        float* mp = Mbuf + ((size_t)b * cN + n) * O + l * VEC;
        if constexpr (VEC == 4){
            *(float4*)mp = make_float4(mx[0]+w2[0], mx[1]+w2[1], mx[2]+w2[2], mx[3]+w2[3]);
        } else if constexpr (VEC == 2){
            *(float2*)mp = make_float2(mx[0]+w2[0], mx[1]+w2[1]);
        } else {
            *mp = mx[0] + w2[0];
        }
        #pragma unroll
        for(int v = 0; v < VEC; v++){
            lsum[v] += su[v] + (float)cKnn * w2[v];
            lsq[v]  += s2[v] + 2.f * w2[v] * su[v] + (float)cKnn * w2[v] * w2[v];
        }
    }
    int bkt = id & 63;
    #pragma unroll
    for(int v = 0; v < VEC; v++){
        atomicAdd(&bsum[bkt * O + l * VEC + v], lsum[v]);
        atomicAdd(&bsq [bkt * O + l * VEC + v], lsq[v]);
    }
}

// ---------------- reduce buckets -> scale/shift ----------------
template<int O>
__global__ void k_redstats(const float* __restrict__ bsum, const float* __restrict__ bsq,
                           const float* __restrict__ g, const float* __restrict__ bb,
                           float2* __restrict__ stats, float invcnt){
    int o = threadIdx.x;
    if(o >= O) return;
    float s = 0.f, q = 0.f;
    for(int k = 0; k < 64; k++){ s += bsum[k * O + o]; q += bsq[k * O + o]; }
    float m = s * invcnt;
    float v = q * invcnt - m * m;
    float sc = g[o] * rsqrtf(v + F_EPS);
    stats[o] = make_float2(sc, bb[o] - m * sc);
}

// ---------------- fused normalize: catb bf16 + next-layer XHL hi/lo + XX ----------------
template<int O, bool WXT>
__global__ void k_normf(const float* __restrict__ Mbuf, const float2* __restrict__ stats,
                        unsigned short* __restrict__ catb, unsigned short* __restrict__ xhl,
                        float* __restrict__ xx, int ooff){
    __shared__ float part[4];
    int tid = threadIdx.x;
    size_t i = (size_t)blockIdx.x * 256 + tid;
    int o = i % O;
    size_t bn = i / O;
    float2 st = stats[o];
    float y = lrelu(Mbuf[i] * st.x + st.y);
    catb[bn * 512 + ooff + o] = f2bf(y);
    if constexpr (WXT){
        unsigned short h = f2bf(y);
        unsigned short l = f2bf(y - bf2f(h));
        xhl[bn * 2 * O + o] = h;
        xhl[bn * 2 * O + O + o] = l;
        float s = y * y;
        #pragma unroll
        for(int off = 32; off; off >>= 1) s += __shfl_xor(s, off);
        if constexpr (O == 64){
            if((tid & 63) == 0) xx[bn] = s;
        } else {
            int wv = tid >> 6;
            if((tid & 63) == 0) part[wv] = s;
            __syncthreads();
            if((tid & 127) == 0) xx[bn] = part[wv] + part[wv + 1];
        }
    }
}

// ---------------- bf16 MFMA head GEMM: z[b][o][n] = w5 · cat ----------------
__global__ __launch_bounds__(256) void k_gemm_z_mfma(const unsigned short* __restrict__ W5B,
                                                     const unsigned short* __restrict__ CATB,
                                                     float* __restrict__ z){
    __shared__ unsigned short As[128 * 40];
    __shared__ unsigned short Bs[128 * 40];
    int tid = threadIdx.x;
    int lane = tid & 63, wave = tid >> 6;
    int wm = wave & 1, wn = wave >> 1;
    int n0 = blockIdx.x * 128, o0 = blockIdx.y * 128, b = blockIdx.z;
    const unsigned short* Cb = CATB + (size_t)b * cN * 512;
    int m = lane & 15, quad = lane >> 4;
    f32x4 acc[4][4] = {};

    for(int kk = 0; kk < 16; kk++){
        __syncthreads();
        #pragma unroll
        for(int h = 0; h < 2; h++){
            int cidx = tid + h * 256;
            int row = cidx >> 2, cc = cidx & 3;
            *(uint4*)&As[row*40 + cc*8] = *(const uint4*)(W5B + (size_t)(o0 + row) * 512 + kk*32 + cc*8);
            *(uint4*)&Bs[row*40 + cc*8] = *(const uint4*)(Cb  + (size_t)(n0 + row) * 512 + kk*32 + cc*8);
        }
        __syncthreads();
        bf16x8 af[4], bfr[4];
        #pragma unroll
        for(int t = 0; t < 4; t++){
            af[t]  = ldfrag(&As[(wm*64 + t*16 + m)*40 + quad*8]);
            bfr[t] = ldfrag(&Bs[(wn*64 + t*16 + m)*40 + quad*8]);
        }
        #pragma unroll
        for(int i = 0; i < 4; i++)
            #pragma unroll
            for(int j = 0; j < 4; j++)
                acc[i][j] = __builtin_amdgcn_mfma_f32_16x16x32_bf16(af[i], bfr[j], acc[i][j], 0, 0, 0);
    }
    #pragma unroll
    for(int i = 0; i < 4; i++){
        int r0 = o0 + wm*64 + i*16 + quad*4;
        #pragma unroll
        for(int j = 0; j < 4; j++){
            int col = n0 + wn*64 + j*16 + m;
            #pragma unroll
            for(int r = 0; r < 4; r++)
                z[((size_t)b * 1024 + r0 + r) * cN + col] = acc[i][j][r];
        }
    }
}

// ---------------- z stats per channel ----------------
__global__ void k_zstats(const float* __restrict__ z, const float* __restrict__ g5,
                         const float* __restrict__ b5, float2* __restrict__ stats){
    int o = blockIdx.x;
    int tid = threadIdx.x;
    __shared__ float ss[256], sq[256];
    float s = 0.f, q = 0.f;
    for(int e = tid; e < cB * cN; e += 256){
        int b = e >> 11, n = e & 2047;
        float v = z[((size_t)b * 1024 + o) * cN + n];
        s += v; q += v * v;
    }
    ss[tid] = s; sq[tid] = q; __syncthreads();
    for(int st = 128; st; st >>= 1){
        if(tid < st){ ss[tid] += ss[tid + st]; sq[tid] += sq[tid + st]; }
        __syncthreads();
    }
    if(tid == 0){
        float m = ss[0] / (float)(cB * cN);
        float v = sq[0] / (float)(cB * cN) - m * m;
        float sc = g5[o] * rsqrtf(v + F_EPS);
        stats[o] = make_float2(sc, b5[o] - m * sc);
    }
}

// ---------------- pooling ----------------
__global__ void k_pool(const float* __restrict__ z, const float2* __restrict__ stats,
                       float* __restrict__ p){
    int o = blockIdx.x, b = blockIdx.y;
    int tid = threadIdx.x;
    float2 st = stats[o];
    const float* row = z + ((size_t)b * 1024 + o) * cN;
    float mx = -FLT_MAX, sm = 0.f;
    for(int n = tid; n < cN; n += 256){
        float y = lrelu(row[n] * st.x + st.y);
        mx = fmaxf(mx, y); sm += y;
    }
    __shared__ float smx[256], ssm[256];
    smx[tid] = mx; ssm[tid] = sm; __syncthreads();
    for(int st2 = 128; st2; st2 >>= 1){
        if(tid < st2){ smx[tid] = fmaxf(smx[tid], smx[tid + st2]); ssm[tid] += ssm[tid + st2]; }
        __syncthreads();
    }
    if(tid == 0){
        p[(size_t)b * 2048 + o] = smx[0];
        p[(size_t)b * 2048 + 1024 + o] = ssm[0] * (1.f / cN);
    }
}

// ---------------- FC layers ----------------
__global__ void k_fc1(const float* __restrict__ p, const float* __restrict__ lw1,
                      const float* __restrict__ g6, const float* __restrict__ b6,
                      float* __restrict__ h1){
    int f = blockIdx.x;
    int tid = threadIdx.x;
    const float* wrow = lw1 + (size_t)f * 2048;
    float acc[cB] = {};
    for(int i = tid; i < 2048; i += 64){
        float wv = wrow[i];
        #pragma unroll
        for(int b = 0; b < cB; b++) acc[b] += p[(size_t)b * 2048 + i] * wv;
    }
    #pragma unroll
    for(int b = 0; b < cB; b++){
        float v = acc[b];
        for(int off = 32; off; off >>= 1) v += __shfl_down(v, off);
        acc[b] = v;
    }
    if(tid == 0){
        float m = 0.f;
        #pragma unroll
        for(int b = 0; b < cB; b++) m += acc[b];
        m *= (1.f / cB);
        float var = 0.f;
        #pragma unroll
        for(int b = 0; b < cB; b++){ float d = acc[b] - m; var += d * d; }
        var *= (1.f / cB);
        float sc = g6[f] * rsqrtf(var + F_EPS);
        float sh = b6[f] - m * sc;
        #pragma unroll
        for(int b = 0; b < cB; b++) h1[(size_t)b * 512 + f] = lrelu(acc[b] * sc + sh);
    }
}

__global__ void k_fc2(const float* __restrict__ h1, const float* __restrict__ lw2,
                      const float* __restrict__ lb2, const float* __restrict__ g7,
                      const float* __restrict__ b7, float* __restrict__ h2){
    int f = blockIdx.x;
    int tid = threadIdx.x;
    const float* wrow = lw2 + (size_t)f * 512;
    float acc[cB] = {};
    for(int i = tid; i < 512; i += 64){
        float wv = wrow[i];
        #pragma unroll
        for(int b = 0; b < cB; b++) acc[b] += h1[(size_t)b * 512 + i] * wv;
    }
    #pragma unroll
    for(int b = 0; b < cB; b++){
        float v = acc[b];
        for(int off = 32; off; off >>= 1) v += __shfl_down(v, off);
        acc[b] = v;
    }
    if(tid == 0){
        float bias = lb2[f];
        #pragma unroll
        for(int b = 0; b < cB; b++) acc[b] += bias;
        float m = 0.f;
        #pragma unroll
        for(int b = 0; b < cB; b++) m += acc[b];
        m *= (1.f / cB);
        float var = 0.f;
        #pragma unroll
        for(int b = 0; b < cB; b++){ float d = acc[b] - m; var += d * d; }
        var *= (1.f / cB);
        float sc = g7[f] * rsqrtf(var + F_EPS);
        float sh = b7[f] - m * sc;
        #pragma unroll
        for(int b = 0; b < cB; b++) h2[(size_t)b * 256 + f] = lrelu(acc[b] * sc + sh);
    }
}

__global__ void k_fc3(const float* __restrict__ h2, const float* __restrict__ lw3,
                      const float* __restrict__ lb3, float* __restrict__ out){
    int cls = blockIdx.x;
    int tid = threadIdx.x;
    const float* wrow = lw3 + (size_t)cls * 256;
    float acc[cB] = {};
    for(int i = tid; i < 256; i += 64){
        float wv = wrow[i];
        #pragma unroll
        for(int b = 0; b < cB; b++) acc[b] += h2[(size_t)b * 256 + i] * wv;
    }
    #pragma unroll
    for(int b = 0; b < cB; b++){
        float v = acc[b];
        for(int off = 32; off; off >>= 1) v += __shfl_down(v, off);
        acc[b] = v;
    }
    if(tid == 0){
        float bias = lb3[cls];
        #pragma unroll
        for(int b = 0; b < cB; b++) out[(size_t)b * 40 + cls] = acc[b] + bias;
    }
}

// =====================================================================
extern "C" void kernel_launch(void* const* d_in, const int* in_sizes, int n_in,
                              void* d_out, int out_size, void* d_ws, size_t ws_size,
                              hipStream_t stream){
    (void)in_sizes; (void)n_in; (void)out_size; (void)ws_size;
    const float* x   = (const float*)d_in[0];
    const float* w1  = (const float*)d_in[1];
    const float* w2  = (const float*)d_in[2];
    const float* w3  = (const float*)d_in[3];
    const float* w4  = (const float*)d_in[4];
    const float* w5  = (const float*)d_in[5];
    const float* lw1 = (const float*)d_in[6];
    const float* lw2 = (const float*)d_in[7];
    const float* lb2 = (const float*)d_in[8];
    const float* lw3 = (const float*)d_in[9];
    const float* lb3 = (const float*)d_in[10];
    const float* g1 = (const float*)d_in[11]; const float* b1 = (const float*)d_in[12];
    const float* g2 = (const float*)d_in[13]; const float* b2 = (const float*)d_in[14];
    const float* g3 = (const float*)d_in[15]; const float* b3 = (const float*)d_in[16];
    const float* g4 = (const float*)d_in[17]; const float* b4 = (const float*)d_in[18];
    const float* g5 = (const float*)d_in[19]; const float* b5 = (const float*)d_in[20];
    const float* g6 = (const float*)d_in[21]; const float* b6 = (const float*)d_in[22];
    const float* g7 = (const float*)d_in[23]; const float* b7 = (const float*)d_in[24];

    char* base = (char*)d_ws;
    size_t off = 0;
    auto alloc = [&](size_t bytes) -> char* {
        char* pp = base + off;
        off += (bytes + 255) & ~(size_t)255;
        return pp;
    };
    float*  SC   = (float*) alloc(sizeof(float) * (size_t)cB * cN * cN);    // 134 MB score buffer
    float*  XT   = (float*) alloc(sizeof(float) * (size_t)cB * cN * 4);
    float*  Z    = (float*) alloc(sizeof(float) * (size_t)cB * 1024 * cN);  // UW + head z
    float*  MB   = (float*) alloc(sizeof(float) * (size_t)cB * cN * 256);
    int*    IDX  = (int*)   alloc(sizeof(int)   * (size_t)cB * cN * cKnn);
    float*  XX   = (float*) alloc(sizeof(float) * (size_t)cB * cN);
    float*  BS   = (float*) alloc(sizeof(float) * 4 * 2 * 64 * 256);
    float2* STATS= (float2*)alloc(sizeof(float2) * 1024);
    float*  WW   = (float*) alloc(sizeof(float) * 4 * 128);
    unsigned short* WHL2 = (unsigned short*)alloc(sizeof(short) * 128 * 128);
    unsigned short* WHL3 = (unsigned short*)alloc(sizeof(short) * 256 * 128);
    unsigned short* WHL4 = (unsigned short*)alloc(sizeof(short) * 512 * 256);
    unsigned short* XHL  = (unsigned short*)alloc(sizeof(short) * (size_t)cB * cN * 256);
    unsigned short* CATB = (unsigned short*)alloc(sizeof(short) * (size_t)cB * cN * 512);
    unsigned short* W5B  = (unsigned short*)alloc(sizeof(short) * 1024 * 512);
    float*  P    = (float*) alloc(sizeof(float) * (size_t)cB * 2048);
    float*  H1   = (float*) alloc(sizeof(float) * (size_t)cB * 512);
    float*  H2   = (float*) alloc(sizeof(float) * (size_t)cB * 256);
    float*  UW   = Z;
    float* BSUM0 = BS + 0 * 2 * 16384, *BSQ0 = BSUM0 + 16384;
    float* BSUM1 = BS + 1 * 2 * 16384, *BSQ1 = BSUM1 + 16384;
    float* BSUM2 = BS + 2 * 2 * 16384, *BSQ2 = BSUM2 + 16384;
    float* BSUM3 = BS + 3 * 2 * 16384, *BSQ3 = BSUM3 + 16384;

    const float invcnt = 1.f / (float)(cB * cN * cKnn);
    dim3 sc1Grid(cN / 64, cN / 64, cB);
    dim3 scmGrid(cN / 128, cN / 128, cB);
    dim3 selGrid(cN / 2, cB);        // 2 rows per block, 2 waves per row
    int gmBlocks = (cN / 16) * cB;

    // ---- prologue ----
    k_transpose3<<<64, 256, 0, stream>>>(x, XT, XX);
    k_prepall<<<(614912 + 255) / 256, 256, 0, stream>>>(w1, w2, w3, w4, w5, WW, WHL2, WHL3, WHL4, W5B);
    hipMemsetAsync(BS, 0, sizeof(float) * 4 * 2 * 16384, stream);

    // ---- layer 1 (Cin=3 pad 4, O=64): fp32 score/uw ----
    k_score<4><<<sc1Grid, 256, 0, stream>>>(XT, XX, SC);
    k_select<<<selGrid, 256, 0, stream>>>(SC, IDX);
    k_uw<4, 128><<<dim3(2, 32, cB), 256, 0, stream>>>(XT, WW, UW);
    k_gmax<64><<<gmBlocks, 256, 0, stream>>>(UW, IDX, MB, BSUM0, BSQ0);
    k_redstats<64><<<1, 256, 0, stream>>>(BSUM0, BSQ0, g1, b1, STATS, invcnt);
    k_normf<64, true><<<(cB * cN * 64) / 256, 256, 0, stream>>>(MB, STATS, CATB, XHL, XX, 0);

    // ---- layer 2 (Cin=64, O=64): split-bf16 MFMA ----
    k_score_mfma<64><<<scmGrid, 256, 0, stream>>>(XHL, XX, SC);
    k_select<<<selGrid, 256, 0, stream>>>(SC, IDX);
    k_uw_mfma<64, 128><<<dim3(1, 16, cB), 256, 0, stream>>>(XHL, WHL2, UW);
    k_gmax<64><<<gmBlocks, 256, 0, stream>>>(UW, IDX, MB, BSUM1, BSQ1);
    k_redstats<64><<<1, 256, 0, stream>>>(BSUM1, BSQ1, g2, b2, STATS, invcnt);
    k_normf<64, true><<<(cB * cN * 64) / 256, 256, 0, stream>>>(MB, STATS, CATB, XHL, XX, 64);

    // ---- layer 3 (Cin=64, O=128) ----
    k_score_mfma<64><<<scmGrid, 256, 0, stream>>>(XHL, XX, SC);
    k_select<<<selGrid, 256, 0, stream>>>(SC, IDX);
    k_uw_mfma<64, 256><<<dim3(2, 16, cB), 256, 0, stream>>>(XHL, WHL3, UW);
    k_gmax<128><<<gmBlocks, 256, 0, stream>>>(UW, IDX, MB, BSUM2, BSQ2);
    k_redstats<128><<<1, 256, 0, stream>>>(BSUM2, BSQ2, g3, b3, STATS, invcnt);
    k_normf<128, true><<<(cB * cN * 128) / 256, 256, 0, stream>>>(MB, STATS, CATB, XHL, XX, 128);

    // ---- layer 4 (Cin=128, O=256) ----
    k_score_mfma<128><<<scmGrid, 256, 0, stream>>>(XHL, XX, SC);
    k_select<<<selGrid, 256, 0, stream>>>(SC, IDX);
    k_uw_mfma<128, 512><<<dim3(4, 16, cB), 256, 0, stream>>>(XHL, WHL4, UW);
    k_gmax<256><<<gmBlocks, 256, 0, stream>>>(UW, IDX, MB, BSUM3, BSQ3);
    k_redstats<256><<<1, 256, 0, stream>>>(BSUM3, BSQ3, g4, b4, STATS, invcnt);
    k_normf<256, false><<<(cB * cN * 256) / 256, 256, 0, stream>>>(MB, STATS, CATB, nullptr, nullptr, 256);

    // ---- head ----
    k_gemm_z_mfma<<<dim3(cN / 128, 1024 / 128, cB), 256, 0, stream>>>(W5B, CATB, Z);
    k_zstats<<<1024, 256, 0, stream>>>(Z, g5, b5, STATS);
    k_pool<<<dim3(1024, cB), 256, 0, stream>>>(Z, STATS, P);
    k_fc1<<<512, 64, 0, stream>>>(P, lw1, g6, b6, H1);
    k_fc2<<<256, 64, 0, stream>>>(H1, lw2, lb2, g7, b7, H2);
    k_fc3<<<40, 64, 0, stream>>>(H2, lw3, lb3, (float*)d_out);
}